// Round 2
// baseline (6941.434 us; speedup 1.0000x reference)
//
#include <hip/hip_runtime.h>
#include <hip/hip_bf16.h>
#include <cstdint>
#include <cstddef>

#define NN 8192
#define BM 128
#define BN 128
#define BK 32

// ---- tiled GEMM geometry ----
#define TM 256          // square output tile
#define TK 32           // K-step
#define NTILES 256      // NN / TK
#define NBLK 32         // NN / TM
#define NTRI 528        // NBLK*(NBLK+1)/2 upper-tri blocks

typedef unsigned short u16;
typedef unsigned int   u32;
typedef __attribute__((ext_vector_type(8))) short bf16x8;   // 8 bf16 = 4 VGPRs
typedef __attribute__((ext_vector_type(4))) unsigned short u16x4;
typedef __attribute__((ext_vector_type(4))) float f32x4;
typedef __attribute__((ext_vector_type(4))) float floatx4;

__device__ __forceinline__ void gload_lds16(const u16* g, u16* l) {
    __builtin_amdgcn_global_load_lds(
        (const __attribute__((address_space(1))) unsigned int*)g,
        (__attribute__((address_space(3))) unsigned int*)l,
        16, 0, 0);
}

__device__ __forceinline__ u16 f32_to_bf16(float f) {
    __hip_bfloat16 h = __float2bfloat16(f);   // RNE
    return *(u16*)&h;
}

__device__ __forceinline__ void write_zero_tile_f32(float* C, int bm, int bn, int t) {
    f32x4 z = (f32x4){0.f, 0.f, 0.f, 0.f};
    #pragma unroll
    for (int p = 0; p < 16; ++p) {
        int c  = t + p * 256;        // f32x4 chunk id; 32 chunks per 128-wide row
        int r  = c >> 5;
        int ch = c & 31;
        *(f32x4*)(C + (size_t)(bm * BM + r) * NN + bn * BN + ch * 4) = z;
    }
}

__device__ __forceinline__ void store_acc_f32(float* C, const floatx4 (&acc)[4][4],
                                              int bm, int bn, int wm, int wn, int lane) {
    const int col0 = bn * BN + wn * 64 + (lane & 15);
    const int rowq = (lane >> 4) * 4;
    #pragma unroll
    for (int i = 0; i < 4; ++i) {
        int rbase = bm * BM + wm * 64 + i * 16 + rowq;
        #pragma unroll
        for (int j = 0; j < 4; ++j) {
            int col = col0 + j * 16;
            #pragma unroll
            for (int r = 0; r < 4; ++r) {
                int row = rbase + r;
                float v = acc[i][j][r];
                if (col < row) v = 0.0f;       // triu mask
                C[(size_t)row * NN + col] = v;
            }
        }
    }
}

// ================= prep kernels (unchanged, verified) =================
__global__ __launch_bounds__(256) void cvt_a(const float* __restrict__ A,
                                             u16* __restrict__ Abf) {
    size_t i = ((size_t)blockIdx.x * 256 + threadIdx.x) * 8;
    f32x4 v0 = *(const f32x4*)(A + i);
    f32x4 v1 = *(const f32x4*)(A + i + 4);
    bf16x8 o;
    #pragma unroll
    for (int e = 0; e < 4; ++e) { o[e] = (short)f32_to_bf16(v0[e]); o[e+4] = (short)f32_to_bf16(v1[e]); }
    *(bf16x8*)(Abf + i) = o;
}

__global__ __launch_bounds__(256) void cvtT_b(const float* __restrict__ B,
                                              u16* __restrict__ BT) {
    __shared__ alignas(16) u16 tile[64][72];   // 144B row stride, 16B-aligned
    const int bi = blockIdx.y;   // k tile
    const int bj = blockIdx.x;   // n tile
    const int t  = threadIdx.x;

    #pragma unroll
    for (int p = 0; p < 4; ++p) {
        int r  = p * 16 + (t >> 4);          // 0..63
        int c4 = t & 15;                     // f32x4 chunk along n
        f32x4 v = *(const f32x4*)(B + (size_t)(bi * 64 + r) * NN + bj * 64 + c4 * 4);
        #pragma unroll
        for (int e = 0; e < 4; ++e)
            tile[c4 * 4 + e][r] = f32_to_bf16(v[e]);
    }
    __syncthreads();
    #pragma unroll
    for (int p = 0; p < 2; ++p) {
        int c  = t + p * 256;
        int cc = c >> 3;
        int ro = c & 7;
        bf16x8 v = *(const bf16x8*)&tile[cc][ro * 8];
        *(bf16x8*)(BT + (size_t)(bj * 64 + cc) * NN + bi * 64 + ro * 8) = v;
    }
}

// ================= 2-slot pipelined GEMM, conflict-free LDS =================
// 256x256 tile, 8 waves (2M x 4N), BK=32.
// LDS: 2-slot double buffer, 64 KiB total -> 2 blocks/CU co-resident.
//   (the co-resident block covers the per-tile vmcnt(0) drain - m103 mechanism)
// Bank swizzle (T2, rule-21 both-sides): 16B chunk c at row r holds global
//   chunk c ^ ((r>>1)&3). Linear gload_lds dest + inverse-XOR global source +
//   XOR on ds_read. 64-lane fragment reads then hit all 8 bank-quads
//   uniformly (8 lanes each) -> conflict-free.
__global__ __launch_bounds__(512, 4) void gemm_triu_2s(const u16* __restrict__ A,
                                                       const u16* __restrict__ BT,
                                                       float* __restrict__ C) {
    // bijective XCD swizzle over 528 upper-tri blocks (528 % 8 == 0)
    const int orig = blockIdx.x;                 // 0..527
    int swz = (orig & 7) * (NTRI / 8) + (orig >> 3);
    int bm = 0;
    while (swz >= NBLK - bm) { swz -= NBLK - bm; ++bm; }
    const int bn = bm + swz;                     // bn >= bm

    const int t    = threadIdx.x;
    const int w    = t >> 6;                     // wave 0..7
    const int lane = t & 63;
    const int wm   = w >> 2;                     // 0..1 : 128-row half
    const int wn   = w & 3;                      // 0..3 : 64-col quarter

    __shared__ alignas(16) u16 As[2 * TM * TK];  // 32 KiB
    __shared__ alignas(16) u16 Bs[2 * TM * TK];  // 32 KiB

    // ---- staging: thread t -> (row = t>>2, lds chunk = t&3).
    // global chunk = (t&3) ^ ((row>>1)&3); row>>1 == t>>3. Same XOR holds for
    // the +128-row second inst (128>>1 = 64, &3 = 0).
    const int srow = t >> 2;                     // 0..127
    const int sq   = (t & 3) ^ ((t >> 3) & 3);   // inverse-swizzled global chunk
    const u16* pA = A  + (size_t)(bm * TM + srow) * NN + sq * 8;
    const u16* pB = BT + (size_t)(bn * TM + srow) * NN + sq * 8;
    u16* lA = As + w * 512;                      // wave-uniform base; lane*16B added by HW
    u16* lB = Bs + w * 512;

#define STAGE_A(buf) do { \
        gload_lds16(pA,                  lA + (buf) * (TM * TK)); \
        gload_lds16(pA + (size_t)128*NN, lA + (buf) * (TM * TK) + 128 * TK); \
        pA += TK; } while (0)
#define STAGE_B(buf) do { \
        gload_lds16(pB,                  lB + (buf) * (TM * TK)); \
        gload_lds16(pB + (size_t)128*NN, lB + (buf) * (TM * TK) + 128 * TK); \
        pB += TK; } while (0)

    // ---- prologue: stage tile 0 into slot 0 ----
    STAGE_A(0); STAGE_B(0);
    asm volatile("s_waitcnt vmcnt(0)" ::: "memory");
    __builtin_amdgcn_s_barrier();

    // ---- fragment addressing: swizzled k-chunk, constant per lane ----
    // row = ...16-aligned... + fr  =>  (row>>1)&3 == (fr>>1)&3 == (lane>>1)&3
    const int fr = lane & 15;
    const int xq = (((lane >> 4) ^ ((lane >> 1) & 3)) << 3);   // u16 offset in row
    const u16* fA = As + (wm * 128 + fr) * TK + xq;
    const u16* fB = Bs + (wn * 64  + fr) * TK + xq;

    floatx4 acc[8][4];
    #pragma unroll
    for (int i = 0; i < 8; ++i)
        #pragma unroll
        for (int j = 0; j < 4; ++j)
            acc[i][j] = (floatx4){0.f, 0.f, 0.f, 0.f};

    for (int g = 0; g < NTILES; ++g) {
        const int bufo = (g & 1) * (TM * TK);

        // issue next-tile stage first: HBM latency hides under reads+MFMA.
        // WAR: slot (g+1)&1 was last read in iter g-1, whose reads completed
        // before its lgkmcnt(0)+barrier.
        if (g + 1 < NTILES) {
            const int nb = (g + 1) & 1;
            STAGE_A(nb); STAGE_B(nb);
        }

        bf16x8 bfr[4], afA[4], afB[4];
        #pragma unroll
        for (int j = 0; j < 4; ++j) bfr[j] = *(const bf16x8*)(fB + bufo + j * 16 * TK);
        #pragma unroll
        for (int i = 0; i < 4; ++i) afA[i] = *(const bf16x8*)(fA + bufo + i * 16 * TK);
        #pragma unroll
        for (int i = 0; i < 4; ++i) afB[i] = *(const bf16x8*)(fA + bufo + (64 + i * 16) * TK);
        asm volatile("s_waitcnt lgkmcnt(0)");
        __builtin_amdgcn_sched_barrier(0);       // rule 18: pin MFMA after the wait
        __builtin_amdgcn_s_setprio(1);
        #pragma unroll
        for (int i = 0; i < 4; ++i)
            #pragma unroll
            for (int j = 0; j < 4; ++j)
                acc[i][j] = __builtin_amdgcn_mfma_f32_16x16x32_bf16(afA[i], bfr[j], acc[i][j], 0, 0, 0);
        #pragma unroll
        for (int i = 0; i < 4; ++i)
            #pragma unroll
            for (int j = 0; j < 4; ++j)
                acc[4 + i][j] = __builtin_amdgcn_mfma_f32_16x16x32_bf16(afB[i], bfr[j], acc[4 + i][j], 0, 0, 0);
        __builtin_amdgcn_s_setprio(0);
        // RAW for next iter: tile g+1's 4 loads drained, then all waves sync.
        asm volatile("s_waitcnt vmcnt(0)" ::: "memory");
        __builtin_amdgcn_s_barrier();
    }
#undef STAGE_A
#undef STAGE_B

    // ---- epilogue: store with triu mask ----
    const int col0 = bn * TM + wn * 64 + (lane & 15);
    const int rowq = (lane >> 4) * 4;
    #pragma unroll
    for (int i = 0; i < 8; ++i) {
        int rbase = bm * TM + wm * 128 + i * 16 + rowq;
        #pragma unroll
        for (int j = 0; j < 4; ++j) {
            int col = col0 + j * 16;
            #pragma unroll
            for (int r = 0; r < 4; ++r) {
                int row = rbase + r;
                float v = acc[i][j][r];
                if (col < row) v = 0.0f;
                C[(size_t)row * NN + col] = v;
            }
        }
    }

    // ---- zero the mirror (strictly-lower) tile ----
    if (bn > bm) {
        float* Cm = C + (size_t)(bn * TM) * NN + bm * TM;
        f32x4 z = (f32x4){0.f, 0.f, 0.f, 0.f};
        #pragma unroll
        for (int p = 0; p < 32; ++p) {
            int c  = p * 512 + t;
            int rr = c >> 6;
            int cc = c & 63;
            *(f32x4*)(Cm + (size_t)rr * NN + cc * 4) = z;
        }
    }
}

// ================= fallback: workspace-free (unchanged, verified) =================
__global__ __launch_bounds__(256) void gemm_triu_nows(const float* __restrict__ A,
                                                      const float* __restrict__ B,
                                                      float* __restrict__ C) {
    const int lin = blockIdx.y * 64 + blockIdx.x;
    const int rg  = lin >> 9;
    const int wi  = lin & 511;
    const int bm  = (rg << 3) | (wi & 7);
    const int bn  = wi >> 3;
    const int t   = threadIdx.x;

    if (bn < bm) { write_zero_tile_f32(C, bm, bn, t); return; }

    __shared__ alignas(16) u16 As[BM * BK];
    __shared__ alignas(16) u16 Bs[BN * BK];
    u32* Bsd = (u32*)Bs;

    const int lane = t & 63;
    const int wave = t >> 6;
    const int wm = wave >> 1;
    const int wn = wave & 1;

    const int ar = t >> 3;
    const int ac = t & 7;
    const float* gA = A + (size_t)(bm * BM + ar) * NN + ac * 4;
    const int dk = t >> 4;
    const int co = t & 15;
    const int dkx = dk ^ ((co & 3) << 2);
    const float* gB = B + (size_t)(2 * dk) * NN + bn * BN + co * 4;

    floatx4 acc[4][4];
    #pragma unroll
    for (int i = 0; i < 4; ++i)
        #pragma unroll
        for (int j = 0; j < 4; ++j)
            acc[i][j] = (floatx4){0.f, 0.f, 0.f, 0.f};

    const int fr = lane & 15;
    const int q  = lane >> 4;
    const bf16x8* fA0 = (const bf16x8*)(As + (wm * 64 + fr) * BK + q * 8);

    f32x4 pa[4], pb0[2], pb1[2];
    #pragma unroll
    for (int p = 0; p < 4; ++p) pa[p] = *(const f32x4*)(gA + (size_t)p * 32 * NN);
    #pragma unroll
    for (int p = 0; p < 2; ++p) {
        pb0[p] = *(const f32x4*)(gB + p * 64);
        pb1[p] = *(const f32x4*)(gB + NN + p * 64);
    }

    for (int k0 = 0; k0 < NN; k0 += BK) {
        __syncthreads();
        #pragma unroll
        for (int p = 0; p < 4; ++p) {
            u16x4 h;
            #pragma unroll
            for (int e = 0; e < 4; ++e) h[e] = f32_to_bf16(pa[p][e]);
            *(u16x4*)(As + (p * 32 + ar) * BK + ac * 4) = h;
        }
        #pragma unroll
        for (int p = 0; p < 2; ++p) {
            #pragma unroll
            for (int e = 0; e < 4; ++e) {
                u32 d = (u32)f32_to_bf16(pb0[p][e]) | ((u32)f32_to_bf16(pb1[p][e]) << 16);
                Bsd[((p * 16 + co) * 4 + e) * (BK / 2) + dkx] = d;
            }
        }
        __syncthreads();

        if (k0 + BK < NN) {
            gA += BK;
            gB += (size_t)BK * NN;
            #pragma unroll
            for (int p = 0; p < 4; ++p) pa[p] = *(const f32x4*)(gA + (size_t)p * 32 * NN);
            #pragma unroll
            for (int p = 0; p < 2; ++p) {
                pb0[p] = *(const f32x4*)(gB + p * 64);
                pb1[p] = *(const f32x4*)(gB + NN + p * 64);
            }
        }

        bf16x8 af[4], bf[4];
        #pragma unroll
        for (int i = 0; i < 4; ++i) af[i] = fA0[i * 16 * BK / 8];
        #pragma unroll
        for (int j = 0; j < 4; ++j) {
            int n  = wn * 64 + j * 16 + fr;
            int qx = q ^ ((n >> 2) & 3);
            bf[j] = *(const bf16x8*)(Bs + n * BK + qx * 8);
        }
        #pragma unroll
        for (int i = 0; i < 4; ++i)
            #pragma unroll
            for (int j = 0; j < 4; ++j)
                acc[i][j] = __builtin_amdgcn_mfma_f32_16x16x32_bf16(af[i], bf[j], acc[i][j], 0, 0, 0);
    }
    store_acc_f32(C, acc, bm, bn, wm, wn, lane);
}

extern "C" void kernel_launch(void* const* d_in, const int* in_sizes, int n_in,
                              void* d_out, int out_size, void* d_ws, size_t ws_size,
                              hipStream_t stream) {
    const float* A = (const float*)d_in[0];
    const float* B = (const float*)d_in[1];
    float* C = (float*)d_out;

    const size_t half = (size_t)NN * NN * sizeof(u16);   // 128 MiB
    if (ws_size >= 2 * half) {
        u16* Abf = (u16*)d_ws;
        u16* BTbf = (u16*)d_ws + (size_t)NN * NN;
        cvt_a<<<32768, 256, 0, stream>>>(A, Abf);
        cvtT_b<<<dim3(128, 128), 256, 0, stream>>>(B, BTbf);
        gemm_triu_2s<<<NTRI, 512, 0, stream>>>(Abf, BTbf, C);
    } else {
        gemm_triu_nows<<<dim3(64, 64), 256, 0, stream>>>(A, B, C);
    }
}

// Round 5
// 1537.942 us; speedup vs baseline: 4.5135x; 4.5135x over previous
//
#include <hip/hip_runtime.h>
#include <hip/hip_bf16.h>
#include <cstdint>
#include <cstddef>

#define NN 8192
#define BM 128
#define BN 128
#define BK 32

// ---- 8-phase kernel geometry ----
#define TM 256          // square output tile
#define TK 32           // K-step
#define NTILES 256      // NN / TK
#define NBLK 32         // NN / TM
#define NTRI 528        // NBLK*(NBLK+1)/2 upper-tri blocks

typedef unsigned short u16;
typedef unsigned int   u32;
typedef __attribute__((ext_vector_type(8))) short bf16x8;   // 8 bf16 = 4 VGPRs
typedef __attribute__((ext_vector_type(4))) unsigned short u16x4;
typedef __attribute__((ext_vector_type(4))) float f32x4;
typedef __attribute__((ext_vector_type(4))) float floatx4;

__device__ __forceinline__ void gload_lds16(const u16* g, u16* l) {
    __builtin_amdgcn_global_load_lds(
        (const __attribute__((address_space(1))) unsigned int*)g,
        (__attribute__((address_space(3))) unsigned int*)l,
        16, 0, 0);
}

__device__ __forceinline__ u16 f32_to_bf16(float f) {
    __hip_bfloat16 h = __float2bfloat16(f);   // RNE
    return *(u16*)&h;
}

__device__ __forceinline__ void write_zero_tile_f32(float* C, int bm, int bn, int t) {
    f32x4 z = (f32x4){0.f, 0.f, 0.f, 0.f};
    #pragma unroll
    for (int p = 0; p < 16; ++p) {
        int c  = t + p * 256;        // f32x4 chunk id; 32 chunks per 128-wide row
        int r  = c >> 5;
        int ch = c & 31;
        *(f32x4*)(C + (size_t)(bm * BM + r) * NN + bn * BN + ch * 4) = z;
    }
}

__device__ __forceinline__ void store_acc_f32(float* C, const floatx4 (&acc)[4][4],
                                              int bm, int bn, int wm, int wn, int lane) {
    const int col0 = bn * BN + wn * 64 + (lane & 15);
    const int rowq = (lane >> 4) * 4;
    #pragma unroll
    for (int i = 0; i < 4; ++i) {
        int rbase = bm * BM + wm * 64 + i * 16 + rowq;
        #pragma unroll
        for (int j = 0; j < 4; ++j) {
            int col = col0 + j * 16;
            #pragma unroll
            for (int r = 0; r < 4; ++r) {
                int row = rbase + r;
                float v = acc[i][j][r];
                if (col < row) v = 0.0f;       // triu mask
                C[(size_t)row * NN + col] = v;
            }
        }
    }
}

// ================= prep kernels =================
__global__ __launch_bounds__(256) void cvt_a(const float* __restrict__ A,
                                             u16* __restrict__ Abf) {
    size_t i = ((size_t)blockIdx.x * 256 + threadIdx.x) * 8;
    f32x4 v0 = *(const f32x4*)(A + i);
    f32x4 v1 = *(const f32x4*)(A + i + 4);
    bf16x8 o;
    #pragma unroll
    for (int e = 0; e < 4; ++e) { o[e] = (short)f32_to_bf16(v0[e]); o[e+4] = (short)f32_to_bf16(v1[e]); }
    *(bf16x8*)(Abf + i) = o;
}

// B (f32, K x N) -> BT (bf16, N x K). LDS-free: in-register 8x4 transpose.
// Thread t: rq = t>>4 -> k = 8rq..8rq+7, c4 = t&15 -> n = 4c4..4c4+3.
// Reads 8 coalesced f32x4; writes 4 bf16x8 (16B/lane). Straight-line, no sync.
__global__ __launch_bounds__(256) void cvtT_b(const float* __restrict__ B,
                                              u16* __restrict__ BT) {
    const int bj = blockIdx.x;   // n tile (64 wide)
    const int bi = blockIdx.y;   // k tile (128 deep)
    const int t  = threadIdx.x;
    const int rq = t >> 4;       // 0..15
    const int c4 = t & 15;       // 0..15

    f32x4 v[8];
    #pragma unroll
    for (int i = 0; i < 8; ++i)
        v[i] = *(const f32x4*)(B + (size_t)(bi * 128 + rq * 8 + i) * NN + bj * 64 + c4 * 4);
    #pragma unroll
    for (int e = 0; e < 4; ++e) {
        bf16x8 o;
        #pragma unroll
        for (int i = 0; i < 8; ++i) o[i] = (short)f32_to_bf16(v[i][e]);
        *(bf16x8*)(BT + (size_t)(bj * 64 + c4 * 4 + e) * NN + bi * 128 + rq * 8) = o;
    }
}

// ================= R1 structure + R2 swizzle =================
// EXACT R1 loop structure (ran on HW: 992 us, passed): 256x256 tile, 8 waves,
// 4-slot LDS ring staged 3 ahead, 2 phases/K-tile, counted vmcnt(8).
// ONLY change: conflict-free LDS addressing (R2-proven, SQ_LDS_BANK_CONFLICT==0):
//   16B chunk c at row r holds global chunk c ^ ((r>>1)&3); linear gload_lds dest
//   + inverse-XOR global source + XOR on ds_read (rule-21 both-sides).
__global__ __launch_bounds__(512, 2) void gemm_triu_8ph(const u16* __restrict__ A,
                                                        const u16* __restrict__ BT,
                                                        float* __restrict__ C) {
    // bijective XCD swizzle over the 528 upper-tri blocks (528 % 8 == 0)
    const int orig = blockIdx.x;                 // 0..527
    int swz = (orig & 7) * (NTRI / 8) + (orig >> 3);
    int bm = 0;
    while (swz >= NBLK - bm) { swz -= NBLK - bm; ++bm; }
    const int bn = bm + swz;                     // bn >= bm

    const int t    = threadIdx.x;
    const int w    = t >> 6;                     // wave 0..7
    const int lane = t & 63;
    const int wm   = w >> 2;                     // 0..1 : 128-row half
    const int wn   = w & 3;                      // 0..3 : 64-col quarter

    __shared__ alignas(16) u16 As[4 * TM * TK];  // 64 KiB, 4 ring slots
    __shared__ alignas(16) u16 Bs[4 * TM * TK];  // 64 KiB

    // staging: thread t -> (row = t>>2, lds chunk = t&3); global chunk inverse-XORed.
    // Second inst covers rows 128..255: ((128+row)>>1)&3 == (row>>1)&3, same mask.
    const int srow = t >> 2;                     // 0..127
    const int sq   = (t & 3) ^ ((t >> 3) & 3);   // inverse-swizzled global chunk
    const u16* pA = A  + (size_t)(bm * TM + srow) * NN + sq * 8;
    const u16* pB = BT + (size_t)(bn * TM + srow) * NN + sq * 8;
    u16* lA = As + w * 512;                      // wave-uniform LDS base (lane*16B added by HW)
    u16* lB = Bs + w * 512;

#define STAGE_A(buf) do { \
        gload_lds16(pA,                  lA + (buf) * (TM * TK)); \
        gload_lds16(pA + (size_t)128*NN, lA + (buf) * (TM * TK) + 128 * TK); \
        pA += TK; } while (0)
#define STAGE_B(buf) do { \
        gload_lds16(pB,                  lB + (buf) * (TM * TK)); \
        gload_lds16(pB + (size_t)128*NN, lB + (buf) * (TM * TK) + 128 * TK); \
        pB += TK; } while (0)

    // prologue: stage tiles 0,1,2 (12 loads)
    STAGE_A(0); STAGE_B(0);
    STAGE_A(1); STAGE_B(1);
    STAGE_A(2); STAGE_B(2);
    asm volatile("s_waitcnt vmcnt(8)" ::: "memory");   // tile 0 landed; 1,2 in flight
    __builtin_amdgcn_s_barrier();

    // fragment addressing: swizzled k-chunk, constant per lane.
    // row = 16-aligned + fr  =>  (row>>1)&3 == (lane>>1)&3
    const int fr = lane & 15;
    const int xq = (((lane >> 4) ^ ((lane >> 1) & 3)) << 3);   // u16 offset in row
    const u16* fA = As + (wm * 128 + fr) * TK + xq;
    const u16* fB = Bs + (wn * 64  + fr) * TK + xq;

    floatx4 acc[8][4];
    #pragma unroll
    for (int i = 0; i < 8; ++i)
        #pragma unroll
        for (int j = 0; j < 4; ++j)
            acc[i][j] = (floatx4){0.f, 0.f, 0.f, 0.f};

    for (int g = 0; g < NTILES; ++g) {
        const int bufo = (g & 3) * (TM * TK);
        const int nbuf = (g + 3) & 3;

        // ======== phase A: rows wm*128 + 0..63 ========
        bf16x8 af[4], bfr[4];
        #pragma unroll
        for (int i = 0; i < 4; ++i) af[i]  = *(const bf16x8*)(fA + bufo + i * 16 * TK);
        #pragma unroll
        for (int j = 0; j < 4; ++j) bfr[j] = *(const bf16x8*)(fB + bufo + j * 16 * TK);
        if (g < NTILES - 3) STAGE_A(nbuf);
        __builtin_amdgcn_s_barrier();
        asm volatile("s_waitcnt lgkmcnt(0)");
        __builtin_amdgcn_sched_barrier(0);
        __builtin_amdgcn_s_setprio(1);
        #pragma unroll
        for (int i = 0; i < 4; ++i)
            #pragma unroll
            for (int j = 0; j < 4; ++j)
                acc[i][j] = __builtin_amdgcn_mfma_f32_16x16x32_bf16(af[i], bfr[j], acc[i][j], 0, 0, 0);
        __builtin_amdgcn_s_setprio(0);
        __builtin_amdgcn_s_barrier();

        // ======== phase B: rows wm*128 + 64..127 ========
        #pragma unroll
        for (int i = 0; i < 4; ++i) af[i] = *(const bf16x8*)(fA + bufo + (64 + i * 16) * TK);
        if (g < NTILES - 3) STAGE_B(nbuf);
        __builtin_amdgcn_s_barrier();
        asm volatile("s_waitcnt lgkmcnt(0)");
        __builtin_amdgcn_sched_barrier(0);
        __builtin_amdgcn_s_setprio(1);
        #pragma unroll
        for (int i = 0; i < 4; ++i)
            #pragma unroll
            for (int j = 0; j < 4; ++j)
                acc[4 + i][j] = __builtin_amdgcn_mfma_f32_16x16x32_bf16(af[i], bfr[j], acc[4 + i][j], 0, 0, 0);
        __builtin_amdgcn_s_setprio(0);
        // group-boundary fence: counted in main loop, drains 8->4->0 at the tail
        if (g < NTILES - 3)       asm volatile("s_waitcnt vmcnt(8)" ::: "memory");
        else if (g == NTILES - 3) asm volatile("s_waitcnt vmcnt(4)" ::: "memory");
        else if (g == NTILES - 2) asm volatile("s_waitcnt vmcnt(0)" ::: "memory");
        __builtin_amdgcn_s_barrier();
    }
#undef STAGE_A
#undef STAGE_B

    // epilogue: store with triu mask
    const int col0 = bn * TM + wn * 64 + (lane & 15);
    const int rowq = (lane >> 4) * 4;
    #pragma unroll
    for (int i = 0; i < 8; ++i) {
        int rbase = bm * TM + wm * 128 + i * 16 + rowq;
        #pragma unroll
        for (int j = 0; j < 4; ++j) {
            int col = col0 + j * 16;
            #pragma unroll
            for (int r = 0; r < 4; ++r) {
                int row = rbase + r;
                float v = acc[i][j][r];
                if (col < row) v = 0.0f;
                C[(size_t)row * NN + col] = v;
            }
        }
    }

    // zero the mirror (strictly-lower) tile
    if (bn > bm) {
        float* Cm = C + (size_t)(bn * TM) * NN + bm * TM;
        f32x4 z = (f32x4){0.f, 0.f, 0.f, 0.f};
        #pragma unroll
        for (int p = 0; p < 32; ++p) {
            int c  = p * 512 + t;        // 16384 16B-chunks in a 256x256 f32 tile
            int rr = c >> 6;
            int cc = c & 63;
            *(f32x4*)(Cm + (size_t)rr * NN + cc * 4) = z;
        }
    }
}

// ================= fallback: workspace-free (unchanged, verified) =================
__global__ __launch_bounds__(256) void gemm_triu_nows(const float* __restrict__ A,
                                                      const float* __restrict__ B,
                                                      float* __restrict__ C) {
    const int lin = blockIdx.y * 64 + blockIdx.x;
    const int rg  = lin >> 9;
    const int wi  = lin & 511;
    const int bm  = (rg << 3) | (wi & 7);
    const int bn  = wi >> 3;
    const int t   = threadIdx.x;

    if (bn < bm) { write_zero_tile_f32(C, bm, bn, t); return; }

    __shared__ alignas(16) u16 As[BM * BK];
    __shared__ alignas(16) u16 Bs[BN * BK];
    u32* Bsd = (u32*)Bs;

    const int lane = t & 63;
    const int wave = t >> 6;
    const int wm = wave >> 1;
    const int wn = wave & 1;

    const int ar = t >> 3;
    const int ac = t & 7;
    const float* gA = A + (size_t)(bm * BM + ar) * NN + ac * 4;
    const int dk = t >> 4;
    const int co = t & 15;
    const int dkx = dk ^ ((co & 3) << 2);
    const float* gB = B + (size_t)(2 * dk) * NN + bn * BN + co * 4;

    floatx4 acc[4][4];
    #pragma unroll
    for (int i = 0; i < 4; ++i)
        #pragma unroll
        for (int j = 0; j < 4; ++j)
            acc[i][j] = (floatx4){0.f, 0.f, 0.f, 0.f};

    const int fr = lane & 15;
    const int q  = lane >> 4;
    const bf16x8* fA0 = (const bf16x8*)(As + (wm * 64 + fr) * BK + q * 8);

    f32x4 pa[4], pb0[2], pb1[2];
    #pragma unroll
    for (int p = 0; p < 4; ++p) pa[p] = *(const f32x4*)(gA + (size_t)p * 32 * NN);
    #pragma unroll
    for (int p = 0; p < 2; ++p) {
        pb0[p] = *(const f32x4*)(gB + p * 64);
        pb1[p] = *(const f32x4*)(gB + NN + p * 64);
    }

    for (int k0 = 0; k0 < NN; k0 += BK) {
        __syncthreads();
        #pragma unroll
        for (int p = 0; p < 4; ++p) {
            u16x4 h;
            #pragma unroll
            for (int e = 0; e < 4; ++e) h[e] = f32_to_bf16(pa[p][e]);
            *(u16x4*)(As + (p * 32 + ar) * BK + ac * 4) = h;
        }
        #pragma unroll
        for (int p = 0; p < 2; ++p) {
            #pragma unroll
            for (int e = 0; e < 4; ++e) {
                u32 d = (u32)f32_to_bf16(pb0[p][e]) | ((u32)f32_to_bf16(pb1[p][e]) << 16);
                Bsd[((p * 16 + co) * 4 + e) * (BK / 2) + dkx] = d;
            }
        }
        __syncthreads();

        if (k0 + BK < NN) {
            gA += BK;
            gB += (size_t)BK * NN;
            #pragma unroll
            for (int p = 0; p < 4; ++p) pa[p] = *(const f32x4*)(gA + (size_t)p * 32 * NN);
            #pragma unroll
            for (int p = 0; p < 2; ++p) {
                pb0[p] = *(const f32x4*)(gB + p * 64);
                pb1[p] = *(const f32x4*)(gB + NN + p * 64);
            }
        }

        bf16x8 af[4], bf[4];
        #pragma unroll
        for (int i = 0; i < 4; ++i) af[i] = fA0[i * 16 * BK / 8];
        #pragma unroll
        for (int j = 0; j < 4; ++j) {
            int n  = wn * 64 + j * 16 + fr;
            int qx = q ^ ((n >> 2) & 3);
            bf[j] = *(const bf16x8*)(Bs + n * BK + qx * 8);
        }
        #pragma unroll
        for (int i = 0; i < 4; ++i)
            #pragma unroll
            for (int j = 0; j < 4; ++j)
                acc[i][j] = __builtin_amdgcn_mfma_f32_16x16x32_bf16(af[i], bf[j], acc[i][j], 0, 0, 0);
    }
    store_acc_f32(C, acc, bm, bn, wm, wn, lane);
}

extern "C" void kernel_launch(void* const* d_in, const int* in_sizes, int n_in,
                              void* d_out, int out_size, void* d_ws, size_t ws_size,
                              hipStream_t stream) {
    const float* A = (const float*)d_in[0];
    const float* B = (const float*)d_in[1];
    float* C = (float*)d_out;

    const size_t half = (size_t)NN * NN * sizeof(u16);   // 128 MiB
    if (ws_size >= 2 * half) {
        u16* Abf = (u16*)d_ws;
        u16* BTbf = (u16*)d_ws + (size_t)NN * NN;
        cvt_a<<<32768, 256, 0, stream>>>(A, Abf);
        cvtT_b<<<dim3(128, 64), 256, 0, stream>>>(B, BTbf);
        gemm_triu_8ph<<<NTRI, 512, 0, stream>>>(Abf, BTbf, C);
    } else {
        gemm_triu_nows<<<dim3(64, 64), 256, 0, stream>>>(A, B, C);
    }
}